// Round 5
// baseline (212.264 us; speedup 1.0000x reference)
//
#include <hip/hip_runtime.h>
#include <hip/hip_bf16.h>
#include <math.h>

// ---------------------------------------------------------------------------
// GAT x2 + folded (v-proj -> out-proj -> fc) + log_softmax
//   Launch graph (5 dispatches): memset -> fused_pre {gemm1 | bin_scatter |
//     fold} -> csr_finalize -> gat_agg64_g2 -> gat_agg32_fin.
//   gemm1: MFMA bf16; rec1[n] = {als f32[8] | pad | h1 fp8[64]} @128B.
//   gat_agg64_g2: OCTO-CLEAN (R18): e=lane>>3, c=lane&7 (one head/lane),
//     feat via uint2; 32-grain issue-all main + masked-32 residual. NO
//     register rotation (R14's regression was rotation, not layout --
//     isolating here). ~85 VALU + 12 VMEM per 32 edges vs quad's ~138+24.
//   csr_finalize: LDS-staged esrc -> coalesced contiguous write-out (R18).
//   gat_agg32_fin: octo, unmasked-32 + masked-32 residual, rec2 64B lines.
//   Lessons: count WAVE instrs not lane-work (R14); rotation costs movs and
//   serializes streams (R14); aligned single-line records win (R15); gather
//   table structure saturated at ~47us (R17: 4.8MB split == 6.4MB combined);
//   independent gather streams when latency-bound (R6/R8), fewer VALU when
//   issue-bound (VALUBusy ~70% now); __shfl = DS op (R7); many short blocks
//   >> few long (R10); independent kernels share a launch (R17).
// ---------------------------------------------------------------------------

#define BSHIFT 7
#define BMASK  ((1 << BSHIFT) - 1)
#define MAXNB  512
#define TILE   8192
#define XST    136
#define SMBYTES 36864
#define LESRC_MAX 6144

typedef __attribute__((ext_vector_type(8))) short short8;
typedef __attribute__((ext_vector_type(4))) float floatx4;
typedef __attribute__((ext_vector_type(2))) float floatx2;

__device__ __forceinline__ unsigned short f2bf(float f) {
    union { float f; unsigned int u; } v; v.f = f;
    unsigned int u = v.u;
    return (unsigned short)((u + 0x7FFFu + ((u >> 16) & 1u)) >> 16);  // RNE
}
__device__ __forceinline__ float lrelu(float e) { return fmaxf(e, 0.2f * e); }
__device__ __forceinline__ float elu(float o) {
    return (o > 0.f) ? o : (__expf(o) - 1.f);
}

// ---------------- fused pre-pass: gemm1 | bucket scatter | weight fold -----
__global__ __launch_bounds__(256) void fused_pre_kernel(
    // gemm1
    const float* __restrict__ x, const float* __restrict__ W,
    const float* __restrict__ a_src, const float* __restrict__ a_dst,
    char* __restrict__ rec1, float* __restrict__ ald, int N, int GB,
    // scatter
    const int* __restrict__ ei, int E, int Et, int NB, int CAP,
    int* __restrict__ gcount, unsigned int* __restrict__ rec, int NT,
    // fold
    const float* __restrict__ in_proj_w, const float* __restrict__ in_proj_b,
    const float* __restrict__ out_proj_w, const float* __restrict__ out_proj_b,
    const float* __restrict__ fc_w, const float* __restrict__ fc_b,
    float* __restrict__ M, float* __restrict__ bf) {
    __shared__ __align__(16) char sm[SMBYTES];
    int t = threadIdx.x;
    int bid = blockIdx.x;
    if (bid < GB) {
        // ---------------- gemm1 ----------------
        unsigned short* xs = (unsigned short*)sm;              // 64*XST
        unsigned short* wt = xs + 64 * XST;                    // 64*XST
        int nb = bid * 64;
#pragma unroll
        for (int r = 0; r < 8; ++r) {
            int p = t + 256 * r;
            int row = p >> 5;
            int c4  = p & 31;
            int n = nb + row;
            float4 v = (n < N) ? ((const float4*)x)[(size_t)n * 32 + c4]
                               : make_float4(0.f, 0.f, 0.f, 0.f);
            unsigned short* dst = &xs[row * XST + c4 * 4];
            dst[0] = f2bf(v.x); dst[1] = f2bf(v.y);
            dst[2] = f2bf(v.z); dst[3] = f2bf(v.w);
        }
        {
            int n = t & 63, kg = t >> 6;
#pragma unroll
            for (int c = 0; c < 4; ++c) {
                int k0 = kg * 32 + c * 8;
                unsigned short* dst = &wt[n * XST + k0];
#pragma unroll
                for (int j = 0; j < 8; ++j)
                    dst[j] = f2bf(W[(k0 + j) * 64 + n]);
            }
        }
        __syncthreads();
        int wave = t >> 6, lane = t & 63;
        int m16 = lane & 15, quad = lane >> 4;
        floatx4 acc[4];
#pragma unroll
        for (int i = 0; i < 4; ++i) acc[i] = (floatx4){0.f, 0.f, 0.f, 0.f};
#pragma unroll
        for (int k = 0; k < 4; ++k) {
            int koff = k * 32 + quad * 8;
            short8 afrag = *(const short8*)&xs[(wave * 16 + m16) * XST + koff];
#pragma unroll
            for (int nt = 0; nt < 4; ++nt) {
                short8 bfrag = *(const short8*)&wt[(nt * 16 + m16) * XST + koff];
                acc[nt] = __builtin_amdgcn_mfma_f32_16x16x32_bf16(afrag, bfrag, acc[nt], 0, 0, 0);
            }
        }
        __syncthreads();
        float* hs = (float*)sm;                // [64][65]
#pragma unroll
        for (int nt = 0; nt < 4; ++nt)
#pragma unroll
            for (int r = 0; r < 4; ++r)
                hs[(wave * 16 + quad * 4 + r) * 65 + nt * 16 + m16] = acc[nt][r];
        __syncthreads();
        float asv = a_src[lane], adv = a_dst[lane];
        for (int itn = 0; itn < 16; ++itn) {
            int nl = wave * 16 + itn;
            int n = nb + nl;
            if (n >= N) break;
            float v = hs[nl * 65 + lane];
            float ps = v * asv, pd = v * adv;
            ps += __shfl_xor(ps, 1); ps += __shfl_xor(ps, 2); ps += __shfl_xor(ps, 4);
            pd += __shfl_xor(pd, 1); pd += __shfl_xor(pd, 2); pd += __shfl_xor(pd, 4);
            if ((lane & 7) == 0) {
                *(float*)(rec1 + (size_t)n * 128 + 4 * (lane >> 3)) = ps;  // als
                ald[n * 8 + (lane >> 3)] = pd;
            }
            if (lane < 16) {                  // pack 4 channels -> fp8x4
                const float* hr = &hs[nl * 65 + lane * 4];
                int pk = __builtin_amdgcn_cvt_pk_fp8_f32(hr[0], hr[1], 0, false);
                pk = __builtin_amdgcn_cvt_pk_fp8_f32(hr[2], hr[3], pk, true);
                *(unsigned*)(rec1 + (size_t)n * 128 + 64 + 4 * lane) = (unsigned)pk;
            }
        }
    } else if (bid < GB + NT) {
        // ---------------- bucket scatter (LDS-staged) ----------------
        unsigned int* lrec = (unsigned int*)sm;            // TILE*4 = 32768
        int* h   = (int*)(sm + TILE * 4);                  // MAXNB*4
        int* cur = (int*)(sm + TILE * 4 + MAXNB * 4);      // MAXNB*4
        for (int i = t; i < NB; i += 256) h[i] = 0;
        int tile0 = (bid - GB) * TILE;
        int cnt = Et - tile0; if (cnt > TILE) cnt = TILE;
        __syncthreads();
        for (int j = t; j < cnt; j += 256) {
            int jj = tile0 + j;
            int srcv, d;
            if (jj < E) { srcv = ei[jj]; d = ei[E + jj]; } else { srcv = jj - E; d = jj - E; }
            lrec[j] = (unsigned)srcv | ((unsigned)d << 16);
            atomicAdd(&h[d >> BSHIFT], 1);
        }
        __syncthreads();
        for (int i = t; i < NB; i += 256)
            cur[i] = h[i] ? atomicAdd(&gcount[i], h[i]) : 0;
        __syncthreads();
        for (int j = t; j < cnt; j += 256) {
            unsigned v = lrec[j];
            int b = v >> (16 + BSHIFT);
            int pos = atomicAdd(&cur[b], 1);
            if (pos < CAP)
                rec[(size_t)b * CAP + pos] =
                    (v & 0xFFFFu) | ((((v >> 16) & BMASK)) << 16);
        }
    } else {
        // ---------------- weight fold ----------------
        float* Wvo = (float*)sm;                 // 1024 floats
        float* bvo = (float*)(sm + 4096);        // 32 floats
        const float* Wv = in_proj_w + 64 * 32;
        const float* bv = in_proj_b + 64;
        for (int idx = t; idx < 1024; idx += 256) {
            int i = idx >> 5, j = idx & 31;
            float acc = 0.f;
            for (int k = 0; k < 32; ++k) acc += out_proj_w[i * 32 + k] * Wv[k * 32 + j];
            Wvo[idx] = acc;
        }
        if (t < 32) {
            float acc = 0.f;
            for (int k = 0; k < 32; ++k) acc += out_proj_w[t * 32 + k] * bv[k];
            bvo[t] = acc + out_proj_b[t];
        }
        __syncthreads();
        for (int idx = t; idx < 16 * 32; idx += 256) {
            int cc = idx >> 5, j = idx & 31;
            float acc = 0.f;
            for (int i = 0; i < 32; ++i) acc += fc_w[cc * 32 + i] * Wvo[i * 32 + j];
            M[idx] = acc;
        }
        if (t < 16) {
            float acc = 0.f;
            for (int i = 0; i < 32; ++i) acc += fc_w[t * 32 + i] * bvo[i];
            bf[t] = acc + fc_b[t];
        }
    }
}

// ---------------- csr finalize: inline prefix scan + LDS-staged esrc ------
__global__ __launch_bounds__(256) void csr_finalize_kernel(
    const unsigned int* __restrict__ rec, const int* __restrict__ gcount,
    int* __restrict__ rowp, unsigned short* __restrict__ esrc,
    int N, int Et, int CAP) {
    __shared__ int h[128];
    __shared__ int nb[128];
    __shared__ int cur[128];
    __shared__ int ssum[256];
    __shared__ unsigned short lesrc[LESRC_MAX];
    int b = blockIdx.x, t = threadIdx.x;
    size_t rbase = (size_t)b * CAP;
    int cnt = gcount[b]; if (cnt > CAP) cnt = CAP;
    if (t < 128) h[t] = 0;
    // inline exclusive prefix: obase = sum of clamped counts of buckets < b
    int acc = 0;
    for (int i = t; i < b; i += 256) {
        int v = gcount[i];
        acc += (v < CAP) ? v : CAP;
    }
    ssum[t] = acc;
    __syncthreads();
    for (int off = 128; off >= 1; off >>= 1) {
        if (t < off) ssum[t] += ssum[t + off];
        __syncthreads();
    }
    int obase = ssum[0];
    for (int i = t; i < cnt; i += 256)
        atomicAdd(&h[(rec[rbase + i] >> 16) & 127], 1);
    __syncthreads();
    if (t == 0) {
        int run = 0;                       // LOCAL offsets within bucket
        for (int i = 0; i < 128; ++i) { nb[i] = run; run += h[i]; }
    }
    __syncthreads();
    if (t < 128) cur[t] = nb[t];
    int n0 = b << BSHIFT;
    if (t < 128 && n0 + t < N) rowp[n0 + t] = obase + nb[t];
    if (b == 0 && t == 0) rowp[N] = Et;
    __syncthreads();
    for (int i = t; i < cnt; i += 256) {
        unsigned r = rec[rbase + i];
        int pos = atomicAdd(&cur[(r >> 16) & 127], 1);
        lesrc[pos] = (unsigned short)(r & 0xFFFFu);
    }
    __syncthreads();
    for (int i = t; i < cnt; i += 256)     // coalesced contiguous write-out
        esrc[obase + i] = lesrc[i];
}

// ---------------- agg layer 1 (OCTO-CLEAN, 32-grain) + fused gemm2 --------
// One wave per node (4 nodes/block). lane = e*8 + c: edge slot e (0..7),
// head c (0..7), channels 8c..8c+7 via one uint2 fp8 gather from rec1
// (128B/node, one L2 line; als f32 at +4c, feat at +64+8c). Main: 32
// edges/iter, ALL loads issued before any consume, NO rotation. Residual:
// masked-32 (clamped), <=1 iteration.
__global__ __launch_bounds__(256) void gat_agg64_g2_kernel(
    const int* __restrict__ rowp, const unsigned short* __restrict__ esrc,
    const char* __restrict__ rec1, const float* __restrict__ ald_arr,
    const float* __restrict__ bias,
    const float* __restrict__ W2, const float* __restrict__ a2s,
    const float* __restrict__ a2d,
    char* __restrict__ rec2, float* __restrict__ ald2, int N) {
    __shared__ __align__(16) float W2p[2][8][32][4];  // [kh][g][l][jj]
    __shared__ __align__(16) float oL[4][64];
    __shared__ __align__(16) float h2L[4][32];
    int t = threadIdx.x;
    for (int idx = t; idx < 2048; idx += 256) {
        int k = idx >> 5, l = idx & 31;
        W2p[k >> 5][(k & 31) >> 2][l][k & 3] = W2[idx];
    }
    __syncthreads();
    const int lane = t & 63;
    const int wv = t >> 6;
    const int e = lane >> 3;             // edge slot 0..7
    const int c = lane & 7;              // head c, channels 8c..8c+7
    const int aoff = 4 * c;              // als f32 byte offset in rec1
    const int foff = 64 + 8 * c;         // feat uint2 byte offset in rec1
    int n = blockIdx.x * 4 + wv;
    if (n >= N) return;
    float aldv = ald_arr[n * 8 + c];
    int beg = rowp[n], end = rowp[n + 1];
    float dA = 0.f, dB = 0.f;
    floatx2 A0 = {0.f, 0.f}, A1 = {0.f, 0.f}, A2 = {0.f, 0.f}, A3 = {0.f, 0.f};
    floatx2 B0 = {0.f, 0.f}, B1 = {0.f, 0.f}, B2 = {0.f, 0.f}, B3 = {0.f, 0.f};
    int i = beg;
    for (; i + 32 <= end; i += 32) {     // 32-grain, fully unmasked
        int s0 = esrc[i + e],      s1 = esrc[i + 8 + e];
        int s2 = esrc[i + 16 + e], s3 = esrc[i + 24 + e];
        const char* r0 = rec1 + (size_t)s0 * 128;
        const char* r1 = rec1 + (size_t)s1 * 128;
        const char* r2 = rec1 + (size_t)s2 * 128;
        const char* r3 = rec1 + (size_t)s3 * 128;
        float e0 = *(const float*)(r0 + aoff), e1 = *(const float*)(r1 + aoff);
        float e2 = *(const float*)(r2 + aoff), e3 = *(const float*)(r3 + aoff);
        uint2 g0 = *(const uint2*)(r0 + foff), g1 = *(const uint2*)(r1 + foff);
        uint2 g2 = *(const uint2*)(r2 + foff), g3 = *(const uint2*)(r3 + foff);
        float w0 = __expf(lrelu(e0 + aldv));
        float w1 = __expf(lrelu(e1 + aldv));
        float w2 = __expf(lrelu(e2 + aldv));
        float w3 = __expf(lrelu(e3 + aldv));
        dA += w0 + w2; dB += w1 + w3;
        A0 += w0 * __builtin_amdgcn_cvt_pk_f32_fp8(g0.x, false);
        A1 += w0 * __builtin_amdgcn_cvt_pk_f32_fp8(g0.x, true);
        A2 += w0 * __builtin_amdgcn_cvt_pk_f32_fp8(g0.y, false);
        A3 += w0 * __builtin_amdgcn_cvt_pk_f32_fp8(g0.y, true);
        B0 += w1 * __builtin_amdgcn_cvt_pk_f32_fp8(g1.x, false);
        B1 += w1 * __builtin_amdgcn_cvt_pk_f32_fp8(g1.x, true);
        B2 += w1 * __builtin_amdgcn_cvt_pk_f32_fp8(g1.y, false);
        B3 += w1 * __builtin_amdgcn_cvt_pk_f32_fp8(g1.y, true);
        A0 += w2 * __builtin_amdgcn_cvt_pk_f32_fp8(g2.x, false);
        A1 += w2 * __builtin_amdgcn_cvt_pk_f32_fp8(g2.x, true);
        A2 += w2 * __builtin_amdgcn_cvt_pk_f32_fp8(g2.y, false);
        A3 += w2 * __builtin_amdgcn_cvt_pk_f32_fp8(g2.y, true);
        B0 += w3 * __builtin_amdgcn_cvt_pk_f32_fp8(g3.x, false);
        B1 += w3 * __builtin_amdgcn_cvt_pk_f32_fp8(g3.x, true);
        B2 += w3 * __builtin_amdgcn_cvt_pk_f32_fp8(g3.y, false);
        B3 += w3 * __builtin_amdgcn_cvt_pk_f32_fp8(g3.y, true);
    }
    for (; i < end; i += 32) {           // masked-32 residual (<=1 iter)
        int i0 = i + e, i1 = i + 8 + e, i2 = i + 16 + e, i3 = i + 24 + e;
        bool v0 = i0 < end, v1 = i1 < end, v2 = i2 < end, v3 = i3 < end;
        int c0 = v0 ? i0 : beg;
        int c1 = v1 ? i1 : beg;
        int c2 = v2 ? i2 : beg;
        int c3 = v3 ? i3 : beg;
        int s0 = esrc[c0], s1 = esrc[c1], s2 = esrc[c2], s3 = esrc[c3];
        const char* r0 = rec1 + (size_t)s0 * 128;
        const char* r1 = rec1 + (size_t)s1 * 128;
        const char* r2 = rec1 + (size_t)s2 * 128;
        const char* r3 = rec1 + (size_t)s3 * 128;
        float e0 = *(const float*)(r0 + aoff), e1 = *(const float*)(r1 + aoff);
        float e2 = *(const float*)(r2 + aoff), e3 = *(const float*)(r3 + aoff);
        uint2 g0 = *(const uint2*)(r0 + foff), g1 = *(const uint2*)(r1 + foff);
        uint2 g2 = *(const uint2*)(r2 + foff), g3 = *(const uint2*)(r3 + foff);
        float w0 = v0 ? __expf(lrelu(e0 + aldv)) : 0.f;
        float w1 = v1 ? __expf(lrelu(e1 + aldv)) : 0.f;
        float w2 = v2 ? __expf(lrelu(e2 + aldv)) : 0.f;
        float w3 = v3 ? __expf(lrelu(e3 + aldv)) : 0.f;
        dA += w0 + w2; dB += w1 + w3;
        A0 += w0 * __builtin_amdgcn_cvt_pk_f32_fp8(g0.x, false);
        A1 += w0 * __builtin_amdgcn_cvt_pk_f32_fp8(g0.x, true);
        A2 += w0 * __builtin_amdgcn_cvt_pk_f32_fp8(g0.y, false);
        A3 += w0 * __builtin_amdgcn_cvt_pk_f32_fp8(g0.y, true);
        B0 += w1 * __builtin_amdgcn_cvt_pk_f32_fp8(g1.x, false);
        B1 += w1 * __builtin_amdgcn_cvt_pk_f32_fp8(g1.x, true);
        B2 += w1 * __builtin_amdgcn_cvt_pk_f32_fp8(g1.y, false);
        B3 += w1 * __builtin_amdgcn_cvt_pk_f32_fp8(g1.y, true);
        A0 += w2 * __builtin_amdgcn_cvt_pk_f32_fp8(g2.x, false);
        A1 += w2 * __builtin_amdgcn_cvt_pk_f32_fp8(g2.x, true);
        A2 += w2 * __builtin_amdgcn_cvt_pk_f32_fp8(g2.y, false);
        A3 += w2 * __builtin_amdgcn_cvt_pk_f32_fp8(g2.y, true);
        B0 += w3 * __builtin_amdgcn_cvt_pk_f32_fp8(g3.x, false);
        B1 += w3 * __builtin_amdgcn_cvt_pk_f32_fp8(g3.x, true);
        B2 += w3 * __builtin_amdgcn_cvt_pk_f32_fp8(g3.y, false);
        B3 += w3 * __builtin_amdgcn_cvt_pk_f32_fp8(g3.y, true);
    }
    float d = dA + dB;
    float P0 = A0.x + B0.x, P1 = A0.y + B0.y;
    float P2 = A1.x + B1.x, P3 = A1.y + B1.y;
    float P4 = A2.x + B2.x, P5 = A2.y + B2.y;
    float P6 = A3.x + B3.x, P7 = A3.y + B3.y;
    d  += __shfl_xor(d, 8);  d  += __shfl_xor(d, 16);  d  += __shfl_xor(d, 32);
    P0 += __shfl_xor(P0, 8); P0 += __shfl_xor(P0, 16); P0 += __shfl_xor(P0, 32);
    P1 += __shfl_xor(P1, 8); P1 += __shfl_xor(P1, 16); P1 += __shfl_xor(P1, 32);
    P2 += __shfl_xor(P2, 8); P2 += __shfl_xor(P2, 16); P2 += __shfl_xor(P2, 32);
    P3 += __shfl_xor(P3, 8); P3 += __shfl_xor(P3, 16); P3 += __shfl_xor(P3, 32);
    P4 += __shfl_xor(P4, 8); P4 += __shfl_xor(P4, 16); P4 += __shfl_xor(P4, 32);
    P5 += __shfl_xor(P5, 8); P5 += __shfl_xor(P5, 16); P5 += __shfl_xor(P5, 32);
    P6 += __shfl_xor(P6, 8); P6 += __shfl_xor(P6, 16); P6 += __shfl_xor(P6, 32);
    P7 += __shfl_xor(P7, 8); P7 += __shfl_xor(P7, 16); P7 += __shfl_xor(P7, 32);
    float inv = 1.f / (d + 1e-16f);
    float4 bv0 = ((const float4*)bias)[2 * c];
    float4 bv1 = ((const float4*)bias)[2 * c + 1];
    float o0 = elu(P0 * inv + bv0.x);
    float o1 = elu(P1 * inv + bv0.y);
    float o2 = elu(P2 * inv + bv0.z);
    float o3 = elu(P3 * inv + bv0.w);
    float o4 = elu(P4 * inv + bv1.x);
    float o5 = elu(P5 * inv + bv1.y);
    float o6 = elu(P6 * inv + bv1.z);
    float o7 = elu(P7 * inv + bv1.w);
    if (lane < 8) {
        *(float4*)&oL[wv][c * 8]     = make_float4(o0, o1, o2, o3);
        *(float4*)&oL[wv][c * 8 + 4] = make_float4(o4, o5, o6, o7);
    }
    // gemm2: h2[l] = sum_k o[k]*W2[k][l]; split-k over wave halves
    const int l = lane & 31, kh = lane >> 5;
    const float* orow = &oL[wv][kh * 32];
    float a0 = 0.f, a1 = 0.f, a2 = 0.f, a3 = 0.f;
#pragma unroll
    for (int g = 0; g < 8; ++g) {
        float4 ov = *(const float4*)&orow[g * 4];
        float4 wv4 = *(const float4*)&W2p[kh][g][l][0];
        a0 += ov.x * wv4.x; a1 += ov.y * wv4.y;
        a2 += ov.z * wv4.z; a3 += ov.w * wv4.w;
    }
    float acc = (a0 + a1) + (a2 + a3);
    acc += __shfl_xor(acc, 32);
    float ps = acc * a2s[l], pd = acc * a2d[l];
    ps += __shfl_xor(ps, 1); ps += __shfl_xor(ps, 2);
    pd += __shfl_xor(pd, 1); pd += __shfl_xor(pd, 2);
    if (lane < 32) {
        h2L[wv][l] = acc;                 // intra-wave LDS bounce for packing
        if ((l & 3) == 0) {
            *(float*)(rec2 + (size_t)n * 64 + 4 * (l >> 2)) = ps;  // als2
            ald2[n * 8 + (l >> 2)] = pd;
        }
    }
    if (lane < 8) {                       // pack 4 channels -> fp8x4
        const float* hr = &h2L[wv][lane * 4];
        int pk = __builtin_amdgcn_cvt_pk_fp8_f32(hr[0], hr[1], 0, false);
        pk = __builtin_amdgcn_cvt_pk_fp8_f32(hr[2], hr[3], pk, true);
        *(unsigned*)(rec2 + (size_t)n * 64 + 32 + 4 * lane) = (unsigned)pk;
    }
}

// ---------------- agg layer 2 (octo, fp8 pk decode) + fused final ---------
// One wave per node (4 nodes/block). lane = e*8 + c. Gathers from rec2
// (64B/node, single cache line). Unmasked-32 main + masked-32 residual.
__global__ __launch_bounds__(256) void gat_agg32_fin_kernel(
    const int* __restrict__ rowp, const unsigned short* __restrict__ esrc,
    const char* __restrict__ rec2, const float* __restrict__ ald_arr,
    const float* __restrict__ bias,
    const float* __restrict__ M, const float* __restrict__ bf,
    float* __restrict__ out, int N) {
    __shared__ __align__(16) float Mp[8][16][4];   // [g][j][jj]
    __shared__ float bfs[16];
    __shared__ __align__(16) float oL[4][32];
    int t = threadIdx.x;
    for (int i = t; i < 512; i += 256) {
        int j = i >> 5, k = i & 31;
        Mp[k >> 2][j][k & 3] = M[i];
    }
    if (t < 16) bfs[t] = bf[t];
    __syncthreads();
    const int lane = t & 63;
    const int wv = t >> 6;
    const int e = lane >> 3;             // edge slot 0..7
    const int c = lane & 7;              // head, channels 4c..4c+3
    const int aoff = 4 * c;              // als2 byte offset in rec2
    const int foff = 32 + 4 * c;         // feat byte offset in rec2
    int n = blockIdx.x * 4 + wv;
    if (n >= N) return;
    float aldv = ald_arr[n * 8 + c];
    int beg = rowp[n], end = rowp[n + 1];
    float d0 = 0.f, d1 = 0.f, d2 = 0.f, d3 = 0.f;
    floatx2 p0a = {0.f, 0.f}, p0b = {0.f, 0.f};
    floatx2 p1a = {0.f, 0.f}, p1b = {0.f, 0.f};
    floatx2 p2a = {0.f, 0.f}, p2b = {0.f, 0.f};
    floatx2 p3a = {0.f, 0.f}, p3b = {0.f, 0.f};
    int base = beg;
    for (; base + 32 <= end; base += 32) {   // unmasked main
        int s0 = esrc[base + e],      s1 = esrc[base + 8 + e];
        int s2 = esrc[base + 16 + e], s3 = esrc[base + 24 + e];
        const char* r0 = rec2 + (size_t)s0 * 64;
        const char* r1 = rec2 + (size_t)s1 * 64;
        const char* r2 = rec2 + (size_t)s2 * 64;
        const char* r3 = rec2 + (size_t)s3 * 64;
        float e0 = *(const float*)(r0 + aoff) + aldv;
        float e1 = *(const float*)(r1 + aoff) + aldv;
        float e2 = *(const float*)(r2 + aoff) + aldv;
        float e3 = *(const float*)(r3 + aoff) + aldv;
        unsigned g0 = *(const unsigned*)(r0 + foff);
        unsigned g1 = *(const unsigned*)(r1 + foff);
        unsigned g2 = *(const unsigned*)(r2 + foff);
        unsigned g3 = *(const unsigned*)(r3 + foff);
        float w0 = __expf(lrelu(e0));
        float w1 = __expf(lrelu(e1));
        float w2 = __expf(lrelu(e2));
        float w3 = __expf(lrelu(e3));
        d0 += w0; d1 += w1; d2 += w2; d3 += w3;
        p0a += w0 * __builtin_amdgcn_cvt_pk_f32_fp8(g0, false);
        p0b += w0 * __builtin_amdgcn_cvt_pk_f32_fp8(g0, true);
        p1a += w1 * __builtin_amdgcn_cvt_pk_f32_fp8(g1, false);
        p1b += w1 * __builtin_amdgcn_cvt_pk_f32_fp8(g1, true);
        p2a += w2 * __builtin_amdgcn_cvt_pk_f32_fp8(g2, false);
        p2b += w2 * __builtin_amdgcn_cvt_pk_f32_fp8(g2, true);
        p3a += w3 * __builtin_amdgcn_cvt_pk_f32_fp8(g3, false);
        p3b += w3 * __builtin_amdgcn_cvt_pk_f32_fp8(g3, true);
    }
    for (; base < end; base += 32) {         // masked residual (<=1 iter)
        int i0 = base + e;
        int i1 = base + 8 + e;
        int i2 = base + 16 + e;
        int i3 = base + 24 + e;
        bool v0 = i0 < end, v1 = i1 < end, v2 = i2 < end, v3 = i3 < end;
        int c0 = v0 ? i0 : beg;
        int c1 = v1 ? i1 : beg;
        int c2 = v2 ? i2 : beg;
        int c3 = v3 ? i3 : beg;
        int s0 = esrc[c0], s1 = esrc[c1], s2 = esrc[c2], s3 = esrc[c3];
        const char* r0 = rec2 + (size_t)s0 * 64;
        const char* r1 = rec2 + (size_t)s1 * 64;
        const char* r2 = rec2 + (size_t)s2 * 64;
        const char* r3 = rec2 + (size_t)s3 * 64;
        float e0 = *(const float*)(r0 + aoff) + aldv;
        float e1 = *(const float*)(r1 + aoff) + aldv;
        float e2 = *(const float*)(r2 + aoff) + aldv;
        float e3 = *(const float*)(r3 + aoff) + aldv;
        unsigned g0 = *(const unsigned*)(r0 + foff);
        unsigned g1 = *(const unsigned*)(r1 + foff);
        unsigned g2 = *(const unsigned*)(r2 + foff);
        unsigned g3 = *(const unsigned*)(r3 + foff);
        float w0 = v0 ? __expf(lrelu(e0)) : 0.f;
        float w1 = v1 ? __expf(lrelu(e1)) : 0.f;
        float w2 = v2 ? __expf(lrelu(e2)) : 0.f;
        float w3 = v3 ? __expf(lrelu(e3)) : 0.f;
        d0 += w0; d1 += w1; d2 += w2; d3 += w3;
        p0a += w0 * __builtin_amdgcn_cvt_pk_f32_fp8(g0, false);
        p0b += w0 * __builtin_amdgcn_cvt_pk_f32_fp8(g0, true);
        p1a += w1 * __builtin_amdgcn_cvt_pk_f32_fp8(g1, false);
        p1b += w1 * __builtin_amdgcn_cvt_pk_f32_fp8(g1, true);
        p2a += w2 * __builtin_amdgcn_cvt_pk_f32_fp8(g2, false);
        p2b += w2 * __builtin_amdgcn_cvt_pk_f32_fp8(g2, true);
        p3a += w3 * __builtin_amdgcn_cvt_pk_f32_fp8(g3, false);
        p3b += w3 * __builtin_amdgcn_cvt_pk_f32_fp8(g3, true);
    }
    float d = (d0 + d1) + (d2 + d3);
    floatx2 Pa = (p0a + p1a) + (p2a + p3a);
    floatx2 Pb = (p0b + p1b) + (p2b + p3b);
    float P0 = Pa.x, P1 = Pa.y, P2 = Pb.x, P3 = Pb.y;
    d  += __shfl_xor(d, 8);  d  += __shfl_xor(d, 16);  d  += __shfl_xor(d, 32);
    P0 += __shfl_xor(P0, 8); P0 += __shfl_xor(P0, 16); P0 += __shfl_xor(P0, 32);
    P1 += __shfl_xor(P1, 8); P1 += __shfl_xor(P1, 16); P1 += __shfl_xor(P1, 32);
    P2 += __shfl_xor(P2, 8); P2 += __shfl_xor(P2, 16); P2 += __shfl_xor(P2, 32);
    P3 += __shfl_xor(P3, 8); P3 += __shfl_xor(P3, 16); P3 += __shfl_xor(P3, 32);
    float inv = 1.f / (d + 1e-16f);
    float4 bv = ((const float4*)bias)[c];
    float o0 = elu(P0 * inv + bv.x);
    float o1 = elu(P1 * inv + bv.y);
    float o2 = elu(P2 * inv + bv.z);
    float o3 = elu(P3 * inv + bv.w);
    if (lane < 8) *(float4*)&oL[wv][c * 4] = make_float4(o0, o1, o2, o3);
    // final: logits[j] = sum_k M[j][k]*o[k] + bf[j]; redundant per group
    const int j = lane & 15;
    const float* orow = oL[wv];
    float a0 = 0.f, a1 = 0.f, a2 = 0.f, a3 = 0.f;
#pragma unroll
    for (int g = 0; g < 8; ++g) {
        float4 ov = *(const float4*)&orow[g * 4];
        float4 mv = *(const float4*)&Mp[g][j][0];
        a0 += ov.x * mv.x; a1 += ov.y * mv.y;
        a2 += ov.z * mv.z; a3 += ov.w * mv.w;
    }
    float logit = (a0 + a1) + (a2 + a3) + bfs[j];
    float mx = logit;
    mx = fmaxf(mx, __shfl_xor(mx, 1));
    mx = fmaxf(mx, __shfl_xor(mx, 2));
    mx = fmaxf(mx, __shfl_xor(mx, 4));
    mx = fmaxf(mx, __shfl_xor(mx, 8));
    float ex = __expf(logit - mx);
    float se = ex;
    se += __shfl_xor(se, 1);
    se += __shfl_xor(se, 2);
    se += __shfl_xor(se, 4);
    se += __shfl_xor(se, 8);
    float res = logit - (mx + __logf(se));
    if (lane < 16) out[(size_t)n * 16 + j] = res;
}

extern "C" void kernel_launch(void* const* d_in, const int* in_sizes, int n_in,
                              void* d_out, int out_size, void* d_ws, size_t ws_size,
                              hipStream_t stream) {
    const float* x   = (const float*)d_in[0];
    const int*   ei  = (const int*)d_in[1];
    const float* W1  = (const float*)d_in[2];
    const float* a1s = (const float*)d_in[3];
    const float* a1d = (const float*)d_in[4];
    const float* b1  = (const float*)d_in[5];
    const float* W2  = (const float*)d_in[6];
    const float* a2s = (const float*)d_in[7];
    const float* a2d = (const float*)d_in[8];
    const float* b2  = (const float*)d_in[9];
    const float* ipw = (const float*)d_in[10];
    const float* ipb = (const float*)d_in[11];
    const float* opw = (const float*)d_in[12];
    const float* opb = (const float*)d_in[13];
    const float* fcw = (const float*)d_in[14];
    const float* fcb = (const float*)d_in[15];
    float* out = (float*)d_out;

    int N = in_sizes[0] / 128;
    int E = in_sizes[1] / 2;
    int Et = E + N;
    int NB = (N + BMASK) >> BSHIFT;
    int NTILES = (Et + TILE - 1) / TILE;
    int GB = (N + 63) / 64;
    // bucket capacity: mean + 12.5% + 256, rounded up (~14 sd slack);
    // clamped to the finalize LDS staging bound.
    int CAP = Et / NB;
    CAP = CAP + CAP / 8 + 256;
    CAP = (CAP + 255) & ~255;
    if (CAP > LESRC_MAX) CAP = LESRC_MAX;

    char* ws = (char*)d_ws;
    size_t off = 0;
    auto alloc = [&](size_t bytes) -> void* {
        void* p = ws + off;
        off += bytes;
        off = (off + 255) & ~(size_t)255;
        return p;
    };
    int*   bcount = (int*)alloc(MAXNB * 4);
    unsigned int*   rec  = (unsigned int*)alloc((size_t)NB * CAP * 4);
    int*   rowp   = (int*)alloc((size_t)(N + 1) * 4);
    unsigned short* esrc = (unsigned short*)alloc((size_t)Et * 2);
    char* rec1   = (char*)alloc((size_t)N * 128);  // {als f32[8] | pad | h1 fp8[64]}
    float* al1d  = (float*)alloc((size_t)N * 8 * 4);
    char* rec2   = (char*)alloc((size_t)N * 64);   // {als2 f32[8] | h2 fp8[32]}
    float* al2d  = (float*)alloc((size_t)N * 8 * 4);
    float* Mf    = (float*)alloc(512 * 4);
    float* bff   = (float*)alloc(16 * 4);
    (void)ws_size; (void)n_in; (void)out_size;

    hipMemsetAsync(bcount, 0, MAXNB * 4, stream);
    fused_pre_kernel<<<GB + NTILES + 1, 256, 0, stream>>>(
        x, W1, a1s, a1d, rec1, al1d, N, GB,
        ei, E, Et, NB, CAP, bcount, rec, NTILES,
        ipw, ipb, opw, opb, fcw, fcb, Mf, bff);
    csr_finalize_kernel<<<NB, 256, 0, stream>>>(rec, bcount, rowp, esrc, N, Et, CAP);

    gat_agg64_g2_kernel<<<(N + 3) / 4, 256, 0, stream>>>(
        rowp, esrc, rec1, al1d, b1, W2, a2s, a2d, rec2, al2d, N);
    gat_agg32_fin_kernel<<<(N + 3) / 4, 256, 0, stream>>>(
        rowp, esrc, rec2, al2d, b2, Mf, bff, out, N);
}

// Round 6
// 206.132 us; speedup vs baseline: 1.0297x; 1.0297x over previous
//
#include <hip/hip_runtime.h>
#include <hip/hip_bf16.h>
#include <math.h>

// ---------------------------------------------------------------------------
// GAT x2 + folded (v-proj -> out-proj -> fc) + log_softmax
//   Launch graph (5 dispatches): memset -> fused_pre {gemm1 | bin_scatter |
//     fold} -> csr_finalize (LDS-staged esrc) -> gat_agg64_g2 -> gat_agg32_fin.
//   gemm1: MFMA bf16; SEPARATE tables: als f32 (1.6MB L2-hot), h1 fp8 (3.2MB).
//   gat_agg64_g2: QUAD layout (R19: octo loses -- latency-bound, streams are
//     the binding resource). FLAT-48 fast path (99.5% of nodes): all 12 esrc
//     then all 24 gathers issued before any consume -> 3 latency hops vs 5.
//     Fallback: 32-grain main + masked-16 residual (deg>48).
//   gat_agg32_fin: octo + FLAT-64 fast path (8 groups), rec2 64B lines.
//   Lessons: count WAVE instrs not lane-work (R14); rotation costs movs
//   (R14); aligned single-line records win (R15); gather-table structure
//   saturated ~47us (R17); LATENCY-BOUND: streams >> fewer VALU (R19 --
//   octo-clean -4.2us regression, VALUBusy fell with dur up); __shfl = DS op
//   (R7); many short blocks >> few long (R10); independent kernels share a
//   launch (R17); LDS-staged coalesced esrc write-out saves ~4us (R19).
// ---------------------------------------------------------------------------

#define BSHIFT 7
#define BMASK  ((1 << BSHIFT) - 1)
#define MAXNB  512
#define TILE   8192
#define XST    136
#define SMBYTES 36864
#define LESRC_MAX 6144

typedef __attribute__((ext_vector_type(8))) short short8;
typedef __attribute__((ext_vector_type(4))) float floatx4;
typedef __attribute__((ext_vector_type(2))) float floatx2;

__device__ __forceinline__ unsigned short f2bf(float f) {
    union { float f; unsigned int u; } v; v.f = f;
    unsigned int u = v.u;
    return (unsigned short)((u + 0x7FFFu + ((u >> 16) & 1u)) >> 16);  // RNE
}
__device__ __forceinline__ float lrelu(float e) { return fmaxf(e, 0.2f * e); }
__device__ __forceinline__ float elu(float o) {
    return (o > 0.f) ? o : (__expf(o) - 1.f);
}

// ---------------- fused pre-pass: gemm1 | bucket scatter | weight fold -----
__global__ __launch_bounds__(256) void fused_pre_kernel(
    // gemm1
    const float* __restrict__ x, const float* __restrict__ W,
    const float* __restrict__ a_src, const float* __restrict__ a_dst,
    unsigned int* __restrict__ h1p, float* __restrict__ als,
    float* __restrict__ ald, int N, int GB,
    // scatter
    const int* __restrict__ ei, int E, int Et, int NB, int CAP,
    int* __restrict__ gcount, unsigned int* __restrict__ rec, int NT,
    // fold
    const float* __restrict__ in_proj_w, const float* __restrict__ in_proj_b,
    const float* __restrict__ out_proj_w, const float* __restrict__ out_proj_b,
    const float* __restrict__ fc_w, const float* __restrict__ fc_b,
    float* __restrict__ M, float* __restrict__ bf) {
    __shared__ __align__(16) char sm[SMBYTES];
    int t = threadIdx.x;
    int bid = blockIdx.x;
    if (bid < GB) {
        // ---------------- gemm1 ----------------
        unsigned short* xs = (unsigned short*)sm;              // 64*XST
        unsigned short* wt = xs + 64 * XST;                    // 64*XST
        int nb = bid * 64;
#pragma unroll
        for (int r = 0; r < 8; ++r) {
            int p = t + 256 * r;
            int row = p >> 5;
            int c4  = p & 31;
            int n = nb + row;
            float4 v = (n < N) ? ((const float4*)x)[(size_t)n * 32 + c4]
                               : make_float4(0.f, 0.f, 0.f, 0.f);
            unsigned short* dst = &xs[row * XST + c4 * 4];
            dst[0] = f2bf(v.x); dst[1] = f2bf(v.y);
            dst[2] = f2bf(v.z); dst[3] = f2bf(v.w);
        }
        {
            int n = t & 63, kg = t >> 6;
#pragma unroll
            for (int c = 0; c < 4; ++c) {
                int k0 = kg * 32 + c * 8;
                unsigned short* dst = &wt[n * XST + k0];
#pragma unroll
                for (int j = 0; j < 8; ++j)
                    dst[j] = f2bf(W[(k0 + j) * 64 + n]);
            }
        }
        __syncthreads();
        int wave = t >> 6, lane = t & 63;
        int m16 = lane & 15, quad = lane >> 4;
        floatx4 acc[4];
#pragma unroll
        for (int i = 0; i < 4; ++i) acc[i] = (floatx4){0.f, 0.f, 0.f, 0.f};
#pragma unroll
        for (int k = 0; k < 4; ++k) {
            int koff = k * 32 + quad * 8;
            short8 afrag = *(const short8*)&xs[(wave * 16 + m16) * XST + koff];
#pragma unroll
            for (int nt = 0; nt < 4; ++nt) {
                short8 bfrag = *(const short8*)&wt[(nt * 16 + m16) * XST + koff];
                acc[nt] = __builtin_amdgcn_mfma_f32_16x16x32_bf16(afrag, bfrag, acc[nt], 0, 0, 0);
            }
        }
        __syncthreads();
        float* hs = (float*)sm;                // [64][65]
#pragma unroll
        for (int nt = 0; nt < 4; ++nt)
#pragma unroll
            for (int r = 0; r < 4; ++r)
                hs[(wave * 16 + quad * 4 + r) * 65 + nt * 16 + m16] = acc[nt][r];
        __syncthreads();
        float asv = a_src[lane], adv = a_dst[lane];
        for (int itn = 0; itn < 16; ++itn) {
            int nl = wave * 16 + itn;
            int n = nb + nl;
            if (n >= N) break;
            float v = hs[nl * 65 + lane];
            float ps = v * asv, pd = v * adv;
            ps += __shfl_xor(ps, 1); ps += __shfl_xor(ps, 2); ps += __shfl_xor(ps, 4);
            pd += __shfl_xor(pd, 1); pd += __shfl_xor(pd, 2); pd += __shfl_xor(pd, 4);
            if ((lane & 7) == 0) {
                als[n * 8 + (lane >> 3)] = ps;
                ald[n * 8 + (lane >> 3)] = pd;
            }
            if (lane < 16) {                  // pack 4 channels -> fp8x4
                const float* hr = &hs[nl * 65 + lane * 4];
                int pk = __builtin_amdgcn_cvt_pk_fp8_f32(hr[0], hr[1], 0, false);
                pk = __builtin_amdgcn_cvt_pk_fp8_f32(hr[2], hr[3], pk, true);
                h1p[(size_t)n * 16 + lane] = (unsigned)pk;
            }
        }
    } else if (bid < GB + NT) {
        // ---------------- bucket scatter (LDS-staged) ----------------
        unsigned int* lrec = (unsigned int*)sm;            // TILE*4 = 32768
        int* h   = (int*)(sm + TILE * 4);                  // MAXNB*4
        int* cur = (int*)(sm + TILE * 4 + MAXNB * 4);      // MAXNB*4
        for (int i = t; i < NB; i += 256) h[i] = 0;
        int tile0 = (bid - GB) * TILE;
        int cnt = Et - tile0; if (cnt > TILE) cnt = TILE;
        __syncthreads();
        for (int j = t; j < cnt; j += 256) {
            int jj = tile0 + j;
            int srcv, d;
            if (jj < E) { srcv = ei[jj]; d = ei[E + jj]; } else { srcv = jj - E; d = jj - E; }
            lrec[j] = (unsigned)srcv | ((unsigned)d << 16);
            atomicAdd(&h[d >> BSHIFT], 1);
        }
        __syncthreads();
        for (int i = t; i < NB; i += 256)
            cur[i] = h[i] ? atomicAdd(&gcount[i], h[i]) : 0;
        __syncthreads();
        for (int j = t; j < cnt; j += 256) {
            unsigned v = lrec[j];
            int b = v >> (16 + BSHIFT);
            int pos = atomicAdd(&cur[b], 1);
            if (pos < CAP)
                rec[(size_t)b * CAP + pos] =
                    (v & 0xFFFFu) | ((((v >> 16) & BMASK)) << 16);
        }
    } else {
        // ---------------- weight fold ----------------
        float* Wvo = (float*)sm;                 // 1024 floats
        float* bvo = (float*)(sm + 4096);        // 32 floats
        const float* Wv = in_proj_w + 64 * 32;
        const float* bv = in_proj_b + 64;
        for (int idx = t; idx < 1024; idx += 256) {
            int i = idx >> 5, j = idx & 31;
            float acc = 0.f;
            for (int k = 0; k < 32; ++k) acc += out_proj_w[i * 32 + k] * Wv[k * 32 + j];
            Wvo[idx] = acc;
        }
        if (t < 32) {
            float acc = 0.f;
            for (int k = 0; k < 32; ++k) acc += out_proj_w[t * 32 + k] * bv[k];
            bvo[t] = acc + out_proj_b[t];
        }
        __syncthreads();
        for (int idx = t; idx < 16 * 32; idx += 256) {
            int cc = idx >> 5, j = idx & 31;
            float acc = 0.f;
            for (int i = 0; i < 32; ++i) acc += fc_w[cc * 32 + i] * Wvo[i * 32 + j];
            M[idx] = acc;
        }
        if (t < 16) {
            float acc = 0.f;
            for (int i = 0; i < 32; ++i) acc += fc_w[t * 32 + i] * bvo[i];
            bf[t] = acc + fc_b[t];
        }
    }
}

// ---------------- csr finalize: inline prefix scan + LDS-staged esrc ------
__global__ __launch_bounds__(256) void csr_finalize_kernel(
    const unsigned int* __restrict__ rec, const int* __restrict__ gcount,
    int* __restrict__ rowp, unsigned short* __restrict__ esrc,
    int N, int Et, int CAP) {
    __shared__ int h[128];
    __shared__ int nb[128];
    __shared__ int cur[128];
    __shared__ int ssum[256];
    __shared__ unsigned short lesrc[LESRC_MAX];
    int b = blockIdx.x, t = threadIdx.x;
    size_t rbase = (size_t)b * CAP;
    int cnt = gcount[b]; if (cnt > CAP) cnt = CAP;
    if (t < 128) h[t] = 0;
    // inline exclusive prefix: obase = sum of clamped counts of buckets < b
    int acc = 0;
    for (int i = t; i < b; i += 256) {
        int v = gcount[i];
        acc += (v < CAP) ? v : CAP;
    }
    ssum[t] = acc;
    __syncthreads();
    for (int off = 128; off >= 1; off >>= 1) {
        if (t < off) ssum[t] += ssum[t + off];
        __syncthreads();
    }
    int obase = ssum[0];
    for (int i = t; i < cnt; i += 256)
        atomicAdd(&h[(rec[rbase + i] >> 16) & 127], 1);
    __syncthreads();
    if (t == 0) {
        int run = 0;                       // LOCAL offsets within bucket
        for (int i = 0; i < 128; ++i) { nb[i] = run; run += h[i]; }
    }
    __syncthreads();
    if (t < 128) cur[t] = nb[t];
    int n0 = b << BSHIFT;
    if (t < 128 && n0 + t < N) rowp[n0 + t] = obase + nb[t];
    if (b == 0 && t == 0) rowp[N] = Et;
    __syncthreads();
    for (int i = t; i < cnt; i += 256) {
        unsigned r = rec[rbase + i];
        int pos = atomicAdd(&cur[(r >> 16) & 127], 1);
        lesrc[pos] = (unsigned short)(r & 0xFFFFu);
    }
    __syncthreads();
    for (int i = t; i < cnt; i += 256)     // coalesced contiguous write-out
        esrc[obase + i] = lesrc[i];
}

// ---------------- agg layer 1 (quad, flat-48 fast path) + fused gemm2 -----
// One wave per node (4 nodes/block). e=lane>>4 (slot), c=lane&15, hd=c>>1.
// deg<=48 (99.5%): ALL 12 esrc -> ALL 24 gathers -> consume (3 latency hops
// vs 5). deg>48: 32-grain unmasked main + masked-16 residual.
// Epilogue writes rec2[n] = {als2 f32[8] | h2 fp8[32]} (64B, one line).
__global__ __launch_bounds__(256) void gat_agg64_g2_kernel(
    const int* __restrict__ rowp, const unsigned short* __restrict__ esrc,
    const unsigned int* __restrict__ feat, const float* __restrict__ als,
    const float* __restrict__ ald_arr, const float* __restrict__ bias,
    const float* __restrict__ W2, const float* __restrict__ a2s,
    const float* __restrict__ a2d,
    char* __restrict__ rec2, float* __restrict__ ald2, int N) {
    __shared__ __align__(16) float W2p[2][8][32][4];  // [kh][g][l][jj]
    __shared__ __align__(16) float oL[4][64];
    __shared__ __align__(16) float h2L[4][32];
    int t = threadIdx.x;
    for (int idx = t; idx < 2048; idx += 256) {
        int k = idx >> 5, l = idx & 31;
        W2p[k >> 5][(k & 31) >> 2][l][k & 3] = W2[idx];
    }
    __syncthreads();
    const int lane = t & 63;
    const int wv = t >> 6;
    const int e = lane >> 4;             // edge slot 0..3
    const int c = lane & 15;             // channel quad
    const int hd = c >> 1;               // head
    int n = blockIdx.x * 4 + wv;
    if (n >= N) return;
    float aldv = ald_arr[n * 8 + hd];
    int beg = rowp[n], end = rowp[n + 1];
    int deg = end - beg;
    float dA = 0.f, dB = 0.f;
    floatx2 p0a = {0.f, 0.f}, p0b = {0.f, 0.f};
    floatx2 p1a = {0.f, 0.f}, p1b = {0.f, 0.f};
    floatx2 p2a = {0.f, 0.f}, p2b = {0.f, 0.f};
    floatx2 p3a = {0.f, 0.f}, p3b = {0.f, 0.f};
    if (deg <= 48) {
        // flat fully-masked path: issue everything, then consume
        int s[12];
#pragma unroll
        for (int g = 0; g < 12; ++g) {
            int p = beg + g * 4 + e;
            s[g] = esrc[(p < end) ? p : beg];
        }
        float ev[12];
        unsigned gg[12];
#pragma unroll
        for (int g = 0; g < 12; ++g) {
            ev[g] = als[s[g] * 8 + hd];
            gg[g] = feat[s[g] * 16 + c];
        }
#pragma unroll
        for (int g = 0; g < 12; ++g) {
            bool vv = (beg + g * 4 + e) < end;
            float w = vv ? __expf(lrelu(ev[g] + aldv)) : 0.f;
            if ((g & 3) == 0) {
                dA += w;
                p0a += w * __builtin_amdgcn_cvt_pk_f32_fp8(gg[g], false);
                p0b += w * __builtin_amdgcn_cvt_pk_f32_fp8(gg[g], true);
            } else if ((g & 3) == 1) {
                dB += w;
                p1a += w * __builtin_amdgcn_cvt_pk_f32_fp8(gg[g], false);
                p1b += w * __builtin_amdgcn_cvt_pk_f32_fp8(gg[g], true);
            } else if ((g & 3) == 2) {
                dA += w;
                p2a += w * __builtin_amdgcn_cvt_pk_f32_fp8(gg[g], false);
                p2b += w * __builtin_amdgcn_cvt_pk_f32_fp8(gg[g], true);
            } else {
                dB += w;
                p3a += w * __builtin_amdgcn_cvt_pk_f32_fp8(gg[g], false);
                p3b += w * __builtin_amdgcn_cvt_pk_f32_fp8(gg[g], true);
            }
        }
    } else {
        int i = beg;
        for (; i + 32 <= end; i += 32) {     // 32-grain, fully unmasked
            int s0 = esrc[i + e],      s1 = esrc[i + 4 + e];
            int s2 = esrc[i + 8 + e],  s3 = esrc[i + 12 + e];
            int s4 = esrc[i + 16 + e], s5 = esrc[i + 20 + e];
            int s6 = esrc[i + 24 + e], s7 = esrc[i + 28 + e];
            float e0 = als[s0 * 8 + hd], e1 = als[s1 * 8 + hd];
            float e2 = als[s2 * 8 + hd], e3 = als[s3 * 8 + hd];
            float e4 = als[s4 * 8 + hd], e5 = als[s5 * 8 + hd];
            float e6 = als[s6 * 8 + hd], e7 = als[s7 * 8 + hd];
            unsigned g0 = feat[s0 * 16 + c], g1 = feat[s1 * 16 + c];
            unsigned g2 = feat[s2 * 16 + c], g3 = feat[s3 * 16 + c];
            unsigned g4 = feat[s4 * 16 + c], g5 = feat[s5 * 16 + c];
            unsigned g6 = feat[s6 * 16 + c], g7 = feat[s7 * 16 + c];
            float w0 = __expf(lrelu(e0 + aldv));
            float w1 = __expf(lrelu(e1 + aldv));
            float w2 = __expf(lrelu(e2 + aldv));
            float w3 = __expf(lrelu(e3 + aldv));
            float w4 = __expf(lrelu(e4 + aldv));
            float w5 = __expf(lrelu(e5 + aldv));
            float w6 = __expf(lrelu(e6 + aldv));
            float w7 = __expf(lrelu(e7 + aldv));
            dA += w0 + w2; dB += w1 + w3;
            dA += w4 + w6; dB += w5 + w7;
            p0a += w0 * __builtin_amdgcn_cvt_pk_f32_fp8(g0, false);
            p0b += w0 * __builtin_amdgcn_cvt_pk_f32_fp8(g0, true);
            p1a += w1 * __builtin_amdgcn_cvt_pk_f32_fp8(g1, false);
            p1b += w1 * __builtin_amdgcn_cvt_pk_f32_fp8(g1, true);
            p2a += w2 * __builtin_amdgcn_cvt_pk_f32_fp8(g2, false);
            p2b += w2 * __builtin_amdgcn_cvt_pk_f32_fp8(g2, true);
            p3a += w3 * __builtin_amdgcn_cvt_pk_f32_fp8(g3, false);
            p3b += w3 * __builtin_amdgcn_cvt_pk_f32_fp8(g3, true);
            p0a += w4 * __builtin_amdgcn_cvt_pk_f32_fp8(g4, false);
            p0b += w4 * __builtin_amdgcn_cvt_pk_f32_fp8(g4, true);
            p1a += w5 * __builtin_amdgcn_cvt_pk_f32_fp8(g5, false);
            p1b += w5 * __builtin_amdgcn_cvt_pk_f32_fp8(g5, true);
            p2a += w6 * __builtin_amdgcn_cvt_pk_f32_fp8(g6, false);
            p2b += w6 * __builtin_amdgcn_cvt_pk_f32_fp8(g6, true);
            p3a += w7 * __builtin_amdgcn_cvt_pk_f32_fp8(g7, false);
            p3b += w7 * __builtin_amdgcn_cvt_pk_f32_fp8(g7, true);
        }
        for (; i < end; i += 16) {           // masked-16 residual (clamped)
            int i0 = i + e, i1 = i + 4 + e, i2 = i + 8 + e, i3 = i + 12 + e;
            bool v0 = i0 < end, v1 = i1 < end, v2 = i2 < end, v3 = i3 < end;
            int c0 = v0 ? i0 : beg;
            int c1 = v1 ? i1 : beg;
            int c2 = v2 ? i2 : beg;
            int c3 = v3 ? i3 : beg;
            int s0 = esrc[c0], s1 = esrc[c1], s2 = esrc[c2], s3 = esrc[c3];
            float e0 = als[s0 * 8 + hd], e1 = als[s1 * 8 + hd];
            float e2 = als[s2 * 8 + hd], e3 = als[s3 * 8 + hd];
            unsigned g0 = feat[s0 * 16 + c], g1 = feat[s1 * 16 + c];
            unsigned g2 = feat[s2 * 16 + c], g3 = feat[s3 * 16 + c];
            float w0 = v0 ? __expf(lrelu(e0 + aldv)) : 0.f;
            float w1 = v1 ? __expf(lrelu(e1 + aldv)) : 0.f;
            float w2 = v2 ? __expf(lrelu(e2 + aldv)) : 0.f;
            float w3 = v3 ? __expf(lrelu(e3 + aldv)) : 0.f;
            dA += w0 + w2; dB += w1 + w3;
            p0a += w0 * __builtin_amdgcn_cvt_pk_f32_fp8(g0, false);
            p0b += w0 * __builtin_amdgcn_cvt_pk_f32_fp8(g0, true);
            p1a += w1 * __builtin_amdgcn_cvt_pk_f32_fp8(g1, false);
            p1b += w1 * __builtin_amdgcn_cvt_pk_f32_fp8(g1, true);
            p2a += w2 * __builtin_amdgcn_cvt_pk_f32_fp8(g2, false);
            p2b += w2 * __builtin_amdgcn_cvt_pk_f32_fp8(g2, true);
            p3a += w3 * __builtin_amdgcn_cvt_pk_f32_fp8(g3, false);
            p3b += w3 * __builtin_amdgcn_cvt_pk_f32_fp8(g3, true);
        }
    }
    float d = dA + dB;
    floatx2 Pa = (p0a + p1a) + (p2a + p3a);
    floatx2 Pb = (p0b + p1b) + (p2b + p3b);
    float P0 = Pa.x, P1 = Pa.y, P2 = Pb.x, P3 = Pb.y;
    d  += __shfl_xor(d, 16);  d  += __shfl_xor(d, 32);
    P0 += __shfl_xor(P0, 16); P0 += __shfl_xor(P0, 32);
    P1 += __shfl_xor(P1, 16); P1 += __shfl_xor(P1, 32);
    P2 += __shfl_xor(P2, 16); P2 += __shfl_xor(P2, 32);
    P3 += __shfl_xor(P3, 16); P3 += __shfl_xor(P3, 32);
    float inv = 1.f / (d + 1e-16f);
    float4 bv = ((const float4*)bias)[c];
    float o0 = elu(P0 * inv + bv.x);
    float o1 = elu(P1 * inv + bv.y);
    float o2 = elu(P2 * inv + bv.z);
    float o3 = elu(P3 * inv + bv.w);
    if (lane < 16) *(float4*)&oL[wv][c * 4] = make_float4(o0, o1, o2, o3);
    // gemm2: h2[l] = sum_k o[k]*W2[k][l]; split-k over wave halves
    const int l = lane & 31, kh = lane >> 5;
    const float* orow = &oL[wv][kh * 32];
    float a0 = 0.f, a1 = 0.f, a2 = 0.f, a3 = 0.f;
#pragma unroll
    for (int g = 0; g < 8; ++g) {
        float4 ov = *(const float4*)&orow[g * 4];
        float4 wv4 = *(const float4*)&W2p[kh][g][l][0];
        a0 += ov.x * wv4.x; a1 += ov.y * wv4.y;
        a2 += ov.z * wv4.z; a3 += ov.w * wv4.w;
    }
    float acc = (a0 + a1) + (a2 + a3);
    acc += __shfl_xor(acc, 32);
    float ps = acc * a2s[l], pd = acc * a2d[l];
    ps += __shfl_xor(ps, 1); ps += __shfl_xor(ps, 2);
    pd += __shfl_xor(pd, 1); pd += __shfl_xor(pd, 2);
    if (lane < 32) {
        h2L[wv][l] = acc;                 // intra-wave LDS bounce for packing
        if ((l & 3) == 0) {
            *(float*)(rec2 + (size_t)n * 64 + 4 * (l >> 2)) = ps;  // als2
            ald2[n * 8 + (l >> 2)] = pd;
        }
    }
    if (lane < 8) {                       // pack 4 channels -> fp8x4
        const float* hr = &h2L[wv][lane * 4];
        int pk = __builtin_amdgcn_cvt_pk_fp8_f32(hr[0], hr[1], 0, false);
        pk = __builtin_amdgcn_cvt_pk_fp8_f32(hr[2], hr[3], pk, true);
        *(unsigned*)(rec2 + (size_t)n * 64 + 32 + 4 * lane) = (unsigned)pk;
    }
}

// ---------------- agg layer 2 (octo, flat-64 fast path) + fused final -----
// One wave per node (4 nodes/block). lane = e*8 + c. Gathers from rec2
// (64B/node, single cache line). deg<=64: flat issue-all path (3 hops).
__global__ __launch_bounds__(256) void gat_agg32_fin_kernel(
    const int* __restrict__ rowp, const unsigned short* __restrict__ esrc,
    const char* __restrict__ rec2, const float* __restrict__ ald_arr,
    const float* __restrict__ bias,
    const float* __restrict__ M, const float* __restrict__ bf,
    float* __restrict__ out, int N) {
    __shared__ __align__(16) float Mp[8][16][4];   // [g][j][jj]
    __shared__ float bfs[16];
    __shared__ __align__(16) float oL[4][32];
    int t = threadIdx.x;
    for (int i = t; i < 512; i += 256) {
        int j = i >> 5, k = i & 31;
        Mp[k >> 2][j][k & 3] = M[i];
    }
    if (t < 16) bfs[t] = bf[t];
    __syncthreads();
    const int lane = t & 63;
    const int wv = t >> 6;
    const int e = lane >> 3;             // edge slot 0..7
    const int c = lane & 7;              // head, channels 4c..4c+3
    const int aoff = 4 * c;              // als2 byte offset in rec2
    const int foff = 32 + 4 * c;         // feat byte offset in rec2
    int n = blockIdx.x * 4 + wv;
    if (n >= N) return;
    float aldv = ald_arr[n * 8 + c];
    int beg = rowp[n], end = rowp[n + 1];
    int deg = end - beg;
    float d0 = 0.f, d1 = 0.f, d2 = 0.f, d3 = 0.f;
    floatx2 p0a = {0.f, 0.f}, p0b = {0.f, 0.f};
    floatx2 p1a = {0.f, 0.f}, p1b = {0.f, 0.f};
    floatx2 p2a = {0.f, 0.f}, p2b = {0.f, 0.f};
    floatx2 p3a = {0.f, 0.f}, p3b = {0.f, 0.f};
    if (deg <= 64) {
        // flat fully-masked path: 8 groups of 8, issue everything first
        int s[8];
#pragma unroll
        for (int g = 0; g < 8; ++g) {
            int p = beg + g * 8 + e;
            s[g] = esrc[(p < end) ? p : beg];
        }
        float ev[8];
        unsigned gg[8];
#pragma unroll
        for (int g = 0; g < 8; ++g) {
            const char* r = rec2 + (size_t)s[g] * 64;
            ev[g] = *(const float*)(r + aoff);
            gg[g] = *(const unsigned*)(r + foff);
        }
#pragma unroll
        for (int g = 0; g < 8; ++g) {
            bool vv = (beg + g * 8 + e) < end;
            float w = vv ? __expf(lrelu(ev[g] + aldv)) : 0.f;
            if ((g & 3) == 0) {
                d0 += w;
                p0a += w * __builtin_amdgcn_cvt_pk_f32_fp8(gg[g], false);
                p0b += w * __builtin_amdgcn_cvt_pk_f32_fp8(gg[g], true);
            } else if ((g & 3) == 1) {
                d1 += w;
                p1a += w * __builtin_amdgcn_cvt_pk_f32_fp8(gg[g], false);
                p1b += w * __builtin_amdgcn_cvt_pk_f32_fp8(gg[g], true);
            } else if ((g & 3) == 2) {
                d2 += w;
                p2a += w * __builtin_amdgcn_cvt_pk_f32_fp8(gg[g], false);
                p2b += w * __builtin_amdgcn_cvt_pk_f32_fp8(gg[g], true);
            } else {
                d3 += w;
                p3a += w * __builtin_amdgcn_cvt_pk_f32_fp8(gg[g], false);
                p3b += w * __builtin_amdgcn_cvt_pk_f32_fp8(gg[g], true);
            }
        }
    } else {
        int base = beg;
        for (; base + 32 <= end; base += 32) {   // unmasked main
            int s0 = esrc[base + e],      s1 = esrc[base + 8 + e];
            int s2 = esrc[base + 16 + e], s3 = esrc[base + 24 + e];
            const char* r0 = rec2 + (size_t)s0 * 64;
            const char* r1 = rec2 + (size_t)s1 * 64;
            const char* r2 = rec2 + (size_t)s2 * 64;
            const char* r3 = rec2 + (size_t)s3 * 64;
            float e0 = *(const float*)(r0 + aoff) + aldv;
            float e1 = *(const float*)(r1 + aoff) + aldv;
            float e2 = *(const float*)(r2 + aoff) + aldv;
            float e3 = *(const float*)(r3 + aoff) + aldv;
            unsigned g0 = *(const unsigned*)(r0 + foff);
            unsigned g1 = *(const unsigned*)(r1 + foff);
            unsigned g2 = *(const unsigned*)(r2 + foff);
            unsigned g3 = *(const unsigned*)(r3 + foff);
            float w0 = __expf(lrelu(e0));
            float w1 = __expf(lrelu(e1));
            float w2 = __expf(lrelu(e2));
            float w3 = __expf(lrelu(e3));
            d0 += w0; d1 += w1; d2 += w2; d3 += w3;
            p0a += w0 * __builtin_amdgcn_cvt_pk_f32_fp8(g0, false);
            p0b += w0 * __builtin_amdgcn_cvt_pk_f32_fp8(g0, true);
            p1a += w1 * __builtin_amdgcn_cvt_pk_f32_fp8(g1, false);
            p1b += w1 * __builtin_amdgcn_cvt_pk_f32_fp8(g1, true);
            p2a += w2 * __builtin_amdgcn_cvt_pk_f32_fp8(g2, false);
            p2b += w2 * __builtin_amdgcn_cvt_pk_f32_fp8(g2, true);
            p3a += w3 * __builtin_amdgcn_cvt_pk_f32_fp8(g3, false);
            p3b += w3 * __builtin_amdgcn_cvt_pk_f32_fp8(g3, true);
        }
        for (; base < end; base += 32) {         // masked residual (<=1 iter)
            int i0 = base + e;
            int i1 = base + 8 + e;
            int i2 = base + 16 + e;
            int i3 = base + 24 + e;
            bool v0 = i0 < end, v1 = i1 < end, v2 = i2 < end, v3 = i3 < end;
            int c0 = v0 ? i0 : beg;
            int c1 = v1 ? i1 : beg;
            int c2 = v2 ? i2 : beg;
            int c3 = v3 ? i3 : beg;
            int s0 = esrc[c0], s1 = esrc[c1], s2 = esrc[c2], s3 = esrc[c3];
            const char* r0 = rec2 + (size_t)s0 * 64;
            const char* r1 = rec2 + (size_t)s1 * 64;
            const char* r2 = rec2 + (size_t)s2 * 64;
            const char* r3 = rec2 + (size_t)s3 * 64;
            float e0 = *(const float*)(r0 + aoff) + aldv;
            float e1 = *(const float*)(r1 + aoff) + aldv;
            float e2 = *(const float*)(r2 + aoff) + aldv;
            float e3 = *(const float*)(r3 + aoff) + aldv;
            unsigned g0 = *(const unsigned*)(r0 + foff);
            unsigned g1 = *(const unsigned*)(r1 + foff);
            unsigned g2 = *(const unsigned*)(r2 + foff);
            unsigned g3 = *(const unsigned*)(r3 + foff);
            float w0 = v0 ? __expf(lrelu(e0)) : 0.f;
            float w1 = v1 ? __expf(lrelu(e1)) : 0.f;
            float w2 = v2 ? __expf(lrelu(e2)) : 0.f;
            float w3 = v3 ? __expf(lrelu(e3)) : 0.f;
            d0 += w0; d1 += w1; d2 += w2; d3 += w3;
            p0a += w0 * __builtin_amdgcn_cvt_pk_f32_fp8(g0, false);
            p0b += w0 * __builtin_amdgcn_cvt_pk_f32_fp8(g0, true);
            p1a += w1 * __builtin_amdgcn_cvt_pk_f32_fp8(g1, false);
            p1b += w1 * __builtin_amdgcn_cvt_pk_f32_fp8(g1, true);
            p2a += w2 * __builtin_amdgcn_cvt_pk_f32_fp8(g2, false);
            p2b += w2 * __builtin_amdgcn_cvt_pk_f32_fp8(g2, true);
            p3a += w3 * __builtin_amdgcn_cvt_pk_f32_fp8(g3, false);
            p3b += w3 * __builtin_amdgcn_cvt_pk_f32_fp8(g3, true);
        }
    }
    float d = (d0 + d1) + (d2 + d3);
    floatx2 Pa = (p0a + p1a) + (p2a + p3a);
    floatx2 Pb = (p0b + p1b) + (p2b + p3b);
    float P0 = Pa.x, P1 = Pa.y, P2 = Pb.x, P3 = Pb.y;
    d  += __shfl_xor(d, 8);  d  += __shfl_xor(d, 16);  d  += __shfl_xor(d, 32);
    P0 += __shfl_xor(P0, 8); P0 += __shfl_xor(P0, 16); P0 += __shfl_xor(P0, 32);
    P1 += __shfl_xor(P1, 8); P1 += __shfl_xor(P1, 16); P1 += __shfl_xor(P1, 32);
    P2 += __shfl_xor(P2, 8); P2 += __shfl_xor(P2, 16); P2 += __shfl_xor(P2, 32);
    P3 += __shfl_xor(P3, 8); P3 += __shfl_xor(P3, 16); P3 += __shfl_xor(P3, 32);
    float inv = 1.f / (d + 1e-16f);
    float4 bv = ((const float4*)bias)[c];
    float o0 = elu(P0 * inv + bv.x);
    float o1 = elu(P1 * inv + bv.y);
    float o2 = elu(P2 * inv + bv.z);
    float o3 = elu(P3 * inv + bv.w);
    if (lane < 8) *(float4*)&oL[wv][c * 4] = make_float4(o0, o1, o2, o3);
    // final: logits[j] = sum_k M[j][k]*o[k] + bf[j]; redundant per group
    const int j = lane & 15;
    const float* orow = oL[wv];
    float a0 = 0.f, a1 = 0.f, a2 = 0.f, a3 = 0.f;
#pragma unroll
    for (int g = 0; g < 8; ++g) {
        float4 ov = *(const float4*)&orow[g * 4];
        float4 mv = *(const float4*)&Mp[g][j][0];
        a0 += ov.x * mv.x; a1 += ov.y * mv.y;
        a2 += ov.z * mv.z; a3 += ov.w * mv.w;
    }
    float logit = (a0 + a1) + (a2 + a3) + bfs[j];
    float mx = logit;
    mx = fmaxf(mx, __shfl_xor(mx, 1));
    mx = fmaxf(mx, __shfl_xor(mx, 2));
    mx = fmaxf(mx, __shfl_xor(mx, 4));
    mx = fmaxf(mx, __shfl_xor(mx, 8));
    float ex = __expf(logit - mx);
    float se = ex;
    se += __shfl_xor(se, 1);
    se += __shfl_xor(se, 2);
    se += __shfl_xor(se, 4);
    se += __shfl_xor(se, 8);
    float res = logit - (mx + __logf(se));
    if (lane < 16) out[(size_t)n * 16 + j] = res;
}

extern "C" void kernel_launch(void* const* d_in, const int* in_sizes, int n_in,
                              void* d_out, int out_size, void* d_ws, size_t ws_size,
                              hipStream_t stream) {
    const float* x   = (const float*)d_in[0];
    const int*   ei  = (const int*)d_in[1];
    const float* W1  = (const float*)d_in[2];
    const float* a1s = (const float*)d_in[3];
    const float* a1d = (const float*)d_in[4];
    const float* b1  = (const float*)d_in[5];
    const float* W2  = (const float*)d_in[6];
    const float* a2s = (const float*)d_in[7];
    const float* a2d = (const float*)d_in[8];
    const float* b2  = (const float*)d_in[9];
    const float* ipw = (const float*)d_in[10];
    const float* ipb = (const float*)d_in[11];
    const float* opw = (const float*)d_in[12];
    const float* opb = (const float*)d_in[13];
    const float* fcw = (const float*)d_in[14];
    const float* fcb = (const float*)d_in[15];
    float* out = (float*)d_out;

    int N = in_sizes[0] / 128;
    int E = in_sizes[1] / 2;
    int Et = E + N;
    int NB = (N + BMASK) >> BSHIFT;
    int NTILES = (Et + TILE - 1) / TILE;
    int GB = (N + 63) / 64;
    // bucket capacity: mean + 12.5% + 256, rounded up (~14 sd slack);
    // clamped to the finalize LDS staging bound.
    int CAP = Et / NB;
    CAP = CAP + CAP / 8 + 256;
    CAP = (CAP + 255) & ~255;
    if (CAP > LESRC_MAX) CAP = LESRC_MAX;

    char* ws = (char*)d_ws;
    size_t off = 0;
    auto alloc = [&](size_t bytes) -> void* {
        void* p = ws + off;
        off += bytes;
        off = (off + 255) & ~(size_t)255;
        return p;
    };
    int*   bcount = (int*)alloc(MAXNB * 4);
    unsigned int*   rec  = (unsigned int*)alloc((size_t)NB * CAP * 4);
    int*   rowp   = (int*)alloc((size_t)(N + 1) * 4);
    unsigned short* esrc = (unsigned short*)alloc((size_t)Et * 2);
    unsigned int* h1p = (unsigned int*)alloc((size_t)N * 16 * 4);  // fp8x4
    float* al1s  = (float*)alloc((size_t)N * 8 * 4);
    float* al1d  = (float*)alloc((size_t)N * 8 * 4);
    char* rec2   = (char*)alloc((size_t)N * 64);   // {als2 f32[8] | h2 fp8[32]}
    float* al2d  = (float*)alloc((size_t)N * 8 * 4);
    float* Mf    = (float*)alloc(512 * 4);
    float* bff   = (float*)alloc(16 * 4);
    (void)ws_size; (void)n_in; (void)out_size;

    hipMemsetAsync(bcount, 0, MAXNB * 4, stream);
    fused_pre_kernel<<<GB + NTILES + 1, 256, 0, stream>>>(
        x, W1, a1s, a1d, h1p, al1s, al1d, N, GB,
        ei, E, Et, NB, CAP, bcount, rec, NTILES,
        ipw, ipb, opw, opb, fcw, fcb, Mf, bff);
    csr_finalize_kernel<<<NB, 256, 0, stream>>>(rec, bcount, rowp, esrc, N, Et, CAP);

    gat_agg64_g2_kernel<<<(N + 3) / 4, 256, 0, stream>>>(
        rowp, esrc, h1p, al1s, al1d, b1, W2, a2s, a2d, rec2, al2d, N);
    gat_agg32_fin_kernel<<<(N + 3) / 4, 256, 0, stream>>>(
        rowp, esrc, rec2, al2d, b2, Mf, bff, out, N);
}